// Round 4
// baseline (576.958 us; speedup 1.0000x reference)
//
#include <hip/hip_runtime.h>
#include <hip/hip_bf16.h>
#include <math.h>

#define N_PTS 8192
#define M_PTS 2048
#define KLAST 10
#define VARS 3
#define OUTD 32
#define D1 80
#define D2 80
#define PB 8          // points per agg block -> 1024 blocks
#define LPTS 2        // output points per last block -> 1024 blocks
#define NT 512        // agg: 8 waves per block
#define NWAVES 8
#define NTL 256       // last: 4 waves per block
#define NWL 4
#define RP 32         // f0b/f1b record pitch in bf16 (64 B = ONE cache line)

// Lane-major fragment-packed weights: fragment f = 64 lanes x 8 bf16, stored
// wp[f*512 + lane*8]. R4: W1/W2 k-order is PERMUTED by sigma(ks,q,e) =
// (2ks+(e>>2))*16 + q*4 + (e&3) so that each layer's B-fragment is exactly
// the lane's OWN packed gelu outputs (D-layout -> B-layout transpose folded
// into the weight pack). This deletes the Tb LDS round-trip that was both
// the per-chunk latency chain (21 LDS ops serial) and the occupancy cap
// (26.6KB LDS). All 31 frags live in LDS (31.7KB), staged once per block.
#define FRAG 512                     // bf16 per fragment (64 lanes x 8)
#define W0F 10                       // L1 frags: 5 cb x 2 kslices
#define W1F 15                       // L2 frags: 5 cb x 3 kslices
#define W2F 6                        // L3 frags: 2 cb x 3 kslices
#define WPACK ((W0F + W1F + W2F) * FRAG)   // 15872 bf16 = 31744 B per set

#define AKEYS (VARS * PB)            // 24 agg keys
#define AKP   (AKEYS + 1)            // 25: bank-spread pitch
#define LKEYS (LPTS * VARS)          // 6 last keys
#define LKP   (LKEYS + 1)            // 7

typedef float f4 __attribute__((ext_vector_type(4)));
typedef short bf16x8 __attribute__((ext_vector_type(8)));

// lean inf-safe tanh-gelu: gelu = x - x*rcp(exp2(x*(A+B*x^2))+1); err ~3e-4.
__device__ __forceinline__ float gelu_f(float x) {
    float x2 = x * x;
    float s = x * __builtin_fmaf(0.1029418f, x2, 2.3022083f);
    float u = __builtin_amdgcn_exp2f(s);
    float r = __builtin_amdgcn_rcpf(u + 1.0f);
    return __builtin_fmaf(-x, r, x);
}
__device__ __forceinline__ unsigned short f2bf(float x) {
    unsigned int u = __float_as_uint(x);
    u += 0x7FFF + ((u >> 16) & 1);
    return (unsigned short)(u >> 16);
}
__device__ __forceinline__ float bf2f(unsigned short h) {
    return __uint_as_float(((unsigned int)h) << 16);
}
// packed RNE f32x2 -> bf16x2 (v_cvt_pk_bf16_f32 on gfx950)
__device__ __forceinline__ int pk2(float a, float b) {
    __hip_bfloat162 h = __float22bfloat162_rn(float2{a, b});
    int r; __builtin_memcpy(&r, &h, 4); return r;
}
__device__ __forceinline__ bf16x8 mk8(int a, int b, int c, int d) {
    int4 v = make_int4(a, b, c, d);
    bf16x8 r; __builtin_memcpy(&r, &v, 16); return r;
}

// One-time pack into lane-major fragment layout.
// W0 k-order: k 0..31 <- W0g rows 4..35 (features), k 32..35 <- rows 0..3.
// W1/W2 k-order: sigma-permuted (see header comment).
__device__ __forceinline__ void pack_weights(
    const float* __restrict__ W0g, const float* __restrict__ W1g,
    const float* __restrict__ W2g, unsigned short* __restrict__ wp, int t)
{
    for (int idx = t; idx < W0F * FRAG; idx += 256) {
        int f = idx >> 9, r = idx & 511;
        int lane = r >> 3, e = r & 7;
        int lm = lane & 15, qd = lane >> 4;
        int cb = f >> 1, ks = f & 1;
        int col = cb * 16 + lm;
        int k = ks * 32 + qd * 8 + e;
        float w = (k < 32) ? W0g[(k + 4) * D1 + col]
                           : ((k < 36) ? W0g[(k - 32) * D1 + col] : 0.0f);
        wp[idx] = f2bf(w);
    }
    for (int idx = t; idx < W1F * FRAG; idx += 256) {
        int f = idx >> 9, r = idx & 511;
        int lane = r >> 3, e = r & 7;
        int lm = lane & 15, qd = lane >> 4;
        int cb = f / 3, ks = f - cb * 3;
        int col = cb * 16 + lm;
        int blk = 2 * ks + (e >> 2);
        int srow = blk * 16 + qd * 4 + (e & 3);
        wp[W0F * FRAG + idx] = f2bf((blk < 5) ? W1g[srow * D1 + col] : 0.0f);
    }
    for (int idx = t; idx < W2F * FRAG; idx += 256) {
        int f = idx >> 9, r = idx & 511;
        int lane = r >> 3, e = r & 7;
        int lm = lane & 15, qd = lane >> 4;
        int cb = f / 3, ks = f - cb * 3;
        int col = cb * 16 + lm;
        int blk = 2 * ks + (e >> 2);
        int srow = blk * 16 + qd * 4 + (e & 3);
        wp[(W0F + W1F) * FRAG + idx] = f2bf((blk < 5) ? W2g[srow * OUTD + col] : 0.0f);
    }
}

#define MFMA16(A, B, C) __builtin_amdgcn_mfma_f32_16x16x32_bf16(A, B, C, 0, 0, 0)
#define GPACK(ACC) make_int2(pk2(gelu_f(ACC.x), gelu_f(ACC.y)), \
                             pk2(gelu_f(ACC.z), gelu_f(ACC.w)))

// Per-wave 16-row chunk MLP, activations fully in registers (no LDS staging).
// Weights from LDS (WA = Wls + lane*8). L3 output atomicAdd'd straight into
// accH[c*kp + key] (all 4 quads of a given lm share ckey). Manual unroll with
// NAMED pk regs (rule: runtime-indexed vector arrays go to scratch).
__device__ __forceinline__ void mlp_chunk(
    int4 featsi, int2 posfi,
    const unsigned short* WA, const float* bs,
    int quad, int ckey, float* accH, int kp)
{
    bf16x8 b1f0; __builtin_memcpy(&b1f0, &featsi, 16);
    int4 pv = make_int4(posfi.x, posfi.y, 0, 0);
    bf16x8 b1f1; __builtin_memcpy(&b1f1, &pv, 16);

    // ---- L1: K=64 (feats+pos+pad) -> 80, gelu, packed to k0..k4 ----
    int2 k0, k1, k2, k3, k4;
#define L1S(CB, PK) { \
    f4 acc = *(const f4*)&bs[(CB) * 16 + quad * 4]; \
    bf16x8 a0 = *(const bf16x8*)&WA[((CB) * 2 + 0) * FRAG]; \
    bf16x8 a1 = *(const bf16x8*)&WA[((CB) * 2 + 1) * FRAG]; \
    acc = MFMA16(a0, b1f0, acc); \
    acc = MFMA16(a1, b1f1, acc); \
    PK = GPACK(acc); }
    L1S(0, k0) L1S(1, k1) L1S(2, k2) L1S(3, k3) L1S(4, k4)
#undef L1S

    // ---- L2: 80(pad 96) -> 80 ; B-frags are direct pk concat (sigma pack) ----
    bf16x8 b20 = mk8(k0.x, k0.y, k1.x, k1.y);
    bf16x8 b21 = mk8(k2.x, k2.y, k3.x, k3.y);
    bf16x8 b22 = mk8(k4.x, k4.y, 0, 0);
    int2 q0, q1, q2, q3, q4;
#define L2S(CB, QK) { \
    f4 acc = *(const f4*)&bs[80 + (CB) * 16 + quad * 4]; \
    const unsigned short* wh = &WA[(W0F + (CB) * 3) * FRAG]; \
    bf16x8 h0 = *(const bf16x8*)&wh[0]; \
    bf16x8 h1 = *(const bf16x8*)&wh[FRAG]; \
    bf16x8 h2 = *(const bf16x8*)&wh[2 * FRAG]; \
    acc = MFMA16(h0, b20, acc); \
    acc = MFMA16(h1, b21, acc); \
    acc = MFMA16(h2, b22, acc); \
    QK = GPACK(acc); }
    L2S(0, q0) L2S(1, q1) L2S(2, q2) L2S(3, q3) L2S(4, q4)
#undef L2S

    // ---- L3: 80(pad 96) -> 32, atomic accumulate ----
    bf16x8 b30 = mk8(q0.x, q0.y, q1.x, q1.y);
    bf16x8 b31 = mk8(q2.x, q2.y, q3.x, q3.y);
    bf16x8 b32 = mk8(q4.x, q4.y, 0, 0);
#define L3S(CB) { \
    f4 acc = *(const f4*)&bs[160 + (CB) * 16 + quad * 4]; \
    const unsigned short* wh = &WA[(W0F + W1F + (CB) * 3) * FRAG]; \
    bf16x8 h0 = *(const bf16x8*)&wh[0]; \
    bf16x8 h1 = *(const bf16x8*)&wh[FRAG]; \
    bf16x8 h2 = *(const bf16x8*)&wh[2 * FRAG]; \
    acc = MFMA16(h0, b30, acc); \
    acc = MFMA16(h1, b31, acc); \
    acc = MFMA16(h2, b32, acc); \
    if (ckey >= 0) { \
        float* ap = accH + ((CB) * 16 + quad * 4) * kp + ckey; \
        atomicAdd(&ap[0], acc.x); \
        atomicAdd(&ap[kp], acc.y); \
        atomicAdd(&ap[2 * kp], acc.z); \
        atomicAdd(&ap[3 * kp], acc.w); \
    } }
    L3S(0) L3S(1)
#undef L3S
}

// ---- merged projection + scan + weight-pack ----
__global__ __launch_bounds__(256) void proj_scan_kernel(
    const float* __restrict__ inp, const float* __restrict__ grid_in,
    const float* __restrict__ W0, const float* __restrict__ b0,
    const float* __restrict__ W1, const float* __restrict__ b1,
    unsigned short* __restrict__ f0b, int* __restrict__ posb,
    const int* __restrict__ counts, int* __restrict__ offsets,
    const float* __restrict__ i0W0, const float* __restrict__ i0W1,
    const float* __restrict__ i0W2, unsigned short* __restrict__ wpack0,
    const float* __restrict__ i1W0, const float* __restrict__ i1W1,
    const float* __restrict__ i1W2, unsigned short* __restrict__ wpack1)
{
    const int t = threadIdx.x;
    if (blockIdx.x == 769) { pack_weights(i0W0, i0W1, i0W2, wpack0, t); return; }
    if (blockIdx.x == 770) { pack_weights(i1W0, i1W1, i1W2, wpack1, t); return; }
    if (blockIdx.x == 768) {
        __shared__ int ws2[4], wx2[4];
        const int lane = t & 63, wave = t >> 6;
        int4 a[8];
#pragma unroll
        for (int i = 0; i < 8; ++i) a[i] = ((const int4*)counts)[t * 8 + i];
        int s = 0;
#pragma unroll
        for (int i = 0; i < 8; ++i) s += a[i].x + a[i].y + a[i].z + a[i].w;
        int x = s;
#pragma unroll
        for (int d = 1; d < 64; d <<= 1) {
            int y = __shfl_up(x, d);
            if (lane >= d) x += y;
        }
        if (lane == 63) ws2[wave] = x;
        __syncthreads();
        if (t == 0) {
            wx2[0] = 0;
            wx2[1] = ws2[0];
            wx2[2] = ws2[0] + ws2[1];
            wx2[3] = ws2[0] + ws2[1] + ws2[2];
        }
        __syncthreads();
        int base = wx2[wave] + (x - s);
#pragma unroll
        for (int i = 0; i < 8; ++i) {
            int4 c = a[i];
            int4 o;
            o.x = base; base += c.x;
            o.y = base; base += c.y;
            o.z = base; base += c.z;
            o.w = base; base += c.w;
            ((int4*)offsets)[t * 8 + i] = o;
        }
        return;
    }
    __shared__ float W0s[8 * 64];
    __shared__ float W1s[64 * OUTD];
    __shared__ float xs[32 * 8];
    __shared__ float H[32 * 64];
    const int r0 = blockIdx.x * 32;
    for (int idx = t; idx < 512; idx += 256) W0s[idx] = W0[idx];
    for (int idx = t; idx < 64 * OUTD; idx += 256) W1s[idx] = W1[idx];
    xs[t] = inp[r0 * 8 + t];
    if (t < 32) {
        int row = r0 + t, n = row / 3;
        posb[n] = pk2(grid_in[2 * n], grid_in[2 * n + 1]);  // dup writes benign
    }
    __syncthreads();
#pragma unroll 1
    for (int p = 0; p < 8; ++p) {
        int o = t + 256 * p, r = o >> 6, col = o & 63;
        float s = b0[col];
#pragma unroll
        for (int k = 0; k < 8; ++k) s += xs[r * 8 + k] * W0s[k * 64 + col];
        H[o] = gelu_f(s);
    }
    __syncthreads();
#pragma unroll 1
    for (int p = 0; p < 4; ++p) {
        int o = t + 256 * p, r = o >> 5, c = o & 31;
        float s = b1[c];
#pragma unroll 8
        for (int k = 0; k < 64; ++k) s += H[r * 64 + k] * W1s[k * OUTD + c];
        int row = r0 + r;
        int n = row / 3, v = row - n * 3;
        f0b[((size_t)(v << 13) + n) * RP + c] = f2bf(s);
    }
}

// ---- edge MLP + owner-computes segment mean ----
// 8 waves x 512 thr, PB=8 -> 1024 blocks; LDS ~36KB -> 4 blocks/CU =
// 32 waves/CU. Gather pipeline 2-deep (index 2 ahead, record 1 ahead).
__global__ __launch_bounds__(512, 8) void agg_kernel(
    const float* __restrict__ grid_in, const unsigned short* __restrict__ f0b,
    const int* __restrict__ posb,
    const int* __restrict__ nbr_index, const int* __restrict__ offsets,
    const int* __restrict__ counts,
    const unsigned short* __restrict__ wpack,
    const float* __restrict__ b0g, const float* __restrict__ b1g,
    const float* __restrict__ b2g,
    unsigned short* __restrict__ f1b)
{
    __shared__ __attribute__((aligned(16))) unsigned short Wls[WPACK];
    __shared__ __attribute__((aligned(16))) float bs[192];
    __shared__ __attribute__((aligned(16))) float accH[OUTD * AKP];
    __shared__ int offs[PB + 1];
    __shared__ int px2b[PB];
    __shared__ float invb[PB];

    const int t = threadIdx.x;
    const int lane = t & 63;
    const int lm = lane & 15, quad = lane >> 4;
    const int wave = t >> 6;
    const int p0 = blockIdx.x * PB;

    // stage all 31 weight fragments into LDS (31744 B)
    for (int idx = t; idx < WPACK / 8; idx += NT)
        ((int4*)Wls)[idx] = ((const int4*)wpack)[idx];
    const unsigned short* WA = Wls + lane * 8;

    for (int idx = t; idx < 192; idx += NT)
        bs[idx] = (idx < 80) ? b0g[idx] : (idx < 160 ? b1g[idx - 80] : b2g[idx - 160]);
    if (t < PB) {
        offs[t] = offsets[p0 + t];
        int c = counts[p0 + t];
        invb[t] = 1.0f / (float)(c > 1 ? c : 1);
        px2b[t] = pk2(grid_in[2 * (p0 + t)], grid_in[2 * (p0 + t) + 1]);
    }
    if (t == PB) offs[PB] = offsets[p0 + PB - 1] + counts[p0 + PB - 1];
    for (int idx = t; idx < OUTD * AKP; idx += NT) accH[idx] = 0.0f;
    __syncthreads();

    const int e0 = offs[0];
    const int cntT = offs[PB] - e0;
    const int Rb = VARS * cntT;
    const int nch = (Rb + 15) >> 4;

    // stage A: index fetch (key + nbr j) — one coalesced global load
    auto fetch_index = [&](int ch2, int& key, int& j) {
        key = -1; j = 0;
        if (ch2 < nch) {
            int myrow = (ch2 << 4) + lm;
            if (myrow < Rb) {
                int myv = (myrow >= 2 * cntT) ? 2 : ((myrow >= cntT) ? 1 : 0);
                int e = e0 + myrow - myv * cntT;
                int lp = 0;
#pragma unroll
                for (int l = 1; l < PB; ++l) lp += (e >= offs[l]);
                key = myv * PB + lp;
                j = nbr_index[e];
            }
        }
    };
    // stage B: record gather — j resident (loaded 1 iteration earlier)
    auto fetch_record = [&](int key, int j, int4& feats, int2& posf) {
        feats = make_int4(0, 0, 0, 0); posf = make_int2(0, 0);
        if (key >= 0) {
            int v = key >> 3, lp = key & 7;   // PB == 8
            feats = ((const int4*)(f0b + ((size_t)(v << 13) + j) * RP))[quad];
            if (quad == 0) posf = make_int2(posb[j], px2b[lp]);
        }
    };

    int keyA, jA, keyB, jB;
    fetch_index(wave, keyA, jA);
    fetch_index(wave + NWAVES, keyB, jB);
    int4 featsA; int2 posfA;
    fetch_record(keyA, jA, featsA, posfA);

    for (int ch = wave; ch < nch; ch += NWAVES) {
        int ckey = keyA; int4 cf = featsA; int2 cp = posfA;
        keyA = keyB; jA = jB;
        fetch_index(ch + 2 * NWAVES, keyB, jB);       // index 2 ahead
        fetch_record(keyA, jA, featsA, posfA);        // record 1 ahead
        mlp_chunk(cf, cp, WA, bs, quad, ckey, accH, AKP);
    }
    __syncthreads();
    for (int idx = t; idx < VARS * PB * OUTD; idx += NT) {
        int key = idx >> 5, c = idx & 31;
        int v = key >> 3, lp = key & 7;     // PB == 8
        size_t rec = ((size_t)(v << 13) + p0 + lp) * RP;
        float val = accH[c * AKP + key] * invb[lp] + bf2f(f0b[rec + c]);
        f1b[rec + c] = f2bf(val);
    }
}

// ---- kNN MLP + mean over K ----
// 256 thr / 4 waves, LPTS=2 -> 1024 blocks (4/CU, LDS ~33KB -> all resident
// = 16 waves/CU), Rb=60 -> 4 chunks = 1 per wave.
__global__ __launch_bounds__(256, 8) void last_kernel(
    const unsigned short* __restrict__ f1b, const int* __restrict__ posb,
    const float* __restrict__ grid_out,
    const int* __restrict__ nbr_last,
    const unsigned short* __restrict__ wpack,
    const float* __restrict__ b0g, const float* __restrict__ b1g,
    const float* __restrict__ b2g,
    float* __restrict__ out)
{
    __shared__ __attribute__((aligned(16))) unsigned short Wls[WPACK];
    __shared__ __attribute__((aligned(16))) float bs[192];
    __shared__ __attribute__((aligned(16))) float accH[OUTD * LKP];
    __shared__ int pxo2b[LPTS];

    const int t = threadIdx.x;
    const int lane = t & 63;
    const int lm = lane & 15, quad = lane >> 4;
    const int wave = t >> 6;
    const int m0 = blockIdx.x * LPTS;

    for (int idx = t; idx < WPACK / 8; idx += NTL)
        ((int4*)Wls)[idx] = ((const int4*)wpack)[idx];
    const unsigned short* WA = Wls + lane * 8;

    for (int idx = t; idx < 192; idx += NTL)
        bs[idx] = (idx < 80) ? b0g[idx] : (idx < 160 ? b1g[idx - 80] : b2g[idx - 160]);
    if (t < LPTS)
        pxo2b[t] = pk2(grid_out[2 * (m0 + t)], grid_out[2 * (m0 + t) + 1]);
    for (int idx = t; idx < OUTD * LKP; idx += NTL) accH[idx] = 0.0f;
    __syncthreads();

    const int Rb = LPTS * VARS * KLAST;   // 60
    const int nch = (Rb + 15) >> 4;       // 4

    auto fetch_index = [&](int ch2, int& key, int& j) {
        key = -1; j = 0;
        if (ch2 < nch) {
            int myrow = (ch2 << 4) + lm;
            if (myrow < Rb) {
                int lp = myrow / 30, rr = myrow - lp * 30;
                int v = rr / KLAST, kk = rr - v * KLAST;
                j = nbr_last[(m0 + lp) * KLAST + kk];
                key = lp * VARS + v;
            }
        }
    };
    auto fetch_record = [&](int key, int j, int4& feats, int2& posf) {
        feats = make_int4(0, 0, 0, 0); posf = make_int2(0, 0);
        if (key >= 0) {
            int lp = key / VARS, v = key - lp * VARS;
            feats = ((const int4*)(f1b + ((size_t)(v << 13) + j) * RP))[quad];
            if (quad == 0) posf = make_int2(posb[j], pxo2b[lp]);
        }
    };

    int keyA, jA, keyB, jB;
    fetch_index(wave, keyA, jA);
    fetch_index(wave + NWL, keyB, jB);
    int4 featsA; int2 posfA;
    fetch_record(keyA, jA, featsA, posfA);

    for (int ch = wave; ch < nch; ch += NWL) {
        int ckey = keyA; int4 cf = featsA; int2 cp = posfA;
        keyA = keyB; jA = jB;
        fetch_index(ch + 2 * NWL, keyB, jB);
        fetch_record(keyA, jA, featsA, posfA);
        mlp_chunk(cf, cp, WA, bs, quad, ckey, accH, LKP);
    }
    __syncthreads();
    for (int idx = t; idx < LPTS * VARS * OUTD; idx += NTL) {
        int key = idx >> 5, c = idx & 31;
        int lp = key / VARS, v = key - lp * VARS;
        out[((size_t)(m0 + lp) * VARS + v) * OUTD + c] =
            accH[c * LKP + key] * (1.0f / KLAST);
    }
}

extern "C" void kernel_launch(void* const* d_in, const int* in_sizes, int n_in,
                              void* d_out, int out_size, void* d_ws, size_t ws_size,
                              hipStream_t stream) {
    const float* inp      = (const float*)d_in[0];
    const float* grid_in  = (const float*)d_in[1];
    const float* grid_out = (const float*)d_in[2];
    const float* pW0 = (const float*)d_in[3];
    const float* pb0 = (const float*)d_in[4];
    const float* pW1 = (const float*)d_in[5];
    const float* pb1 = (const float*)d_in[6];
    const float* i0W0 = (const float*)d_in[7];
    const float* i0b0 = (const float*)d_in[8];
    const float* i0W1 = (const float*)d_in[9];
    const float* i0b1 = (const float*)d_in[10];
    const float* i0W2 = (const float*)d_in[11];
    const float* i0b2 = (const float*)d_in[12];
    const float* i1W0 = (const float*)d_in[13];
    const float* i1b0 = (const float*)d_in[14];
    const float* i1W1 = (const float*)d_in[15];
    const float* i1b1 = (const float*)d_in[16];
    const float* i1W2 = (const float*)d_in[17];
    const float* i1b2 = (const float*)d_in[18];
    const int* nbr_index  = (const int*)d_in[19];
    const int* nbr_counts = (const int*)d_in[21];
    const int* nbr_last   = (const int*)d_in[22];

    unsigned short* f0b = (unsigned short*)d_ws;                      // 3*8192*32 bf16
    unsigned short* f1b = f0b + (size_t)VARS * N_PTS * RP;            // 3*8192*32 bf16
    int* offsets = (int*)(f1b + (size_t)VARS * N_PTS * RP);           // N ints
    int* posb    = offsets + N_PTS;                                   // N ints (bf16x2)
    unsigned short* wpack0 = (unsigned short*)(posb + N_PTS);         // 15872 bf16
    unsigned short* wpack1 = wpack0 + WPACK;                          // 15872 bf16

    proj_scan_kernel<<<771, 256, 0, stream>>>(inp, grid_in, pW0, pb0, pW1, pb1,
                                              f0b, posb, nbr_counts, offsets,
                                              i0W0, i0W1, i0W2, wpack0,
                                              i1W0, i1W1, i1W2, wpack1);
    agg_kernel<<<N_PTS / PB, NT, 0, stream>>>(grid_in, f0b, posb, nbr_index, offsets,
                                              nbr_counts, wpack0,
                                              i0b0, i0b1, i0b2, f1b);
    last_kernel<<<M_PTS / LPTS, NTL, 0, stream>>>(f1b, posb, grid_out, nbr_last, wpack1,
                                                  i1b0, i1b1, i1b2,
                                                  (float*)d_out);
}

// Round 5
// 373.918 us; speedup vs baseline: 1.5430x; 1.5430x over previous
//
#include <hip/hip_runtime.h>
#include <hip/hip_bf16.h>
#include <math.h>

#define N_PTS 8192
#define M_PTS 2048
#define KLAST 10
#define VARS 3
#define OUTD 32
#define D1 80
#define D2 80
#define PB 8          // points per agg block -> 1024 blocks
#define LPTS 2        // output points per last block -> 1024 blocks
#define NT 512        // agg: 8 waves per block
#define NWAVES 8
#define NTL 256       // last: 4 waves per block
#define NWL 4
#define RP 32         // f0b/f1b record pitch in bf16 (64 B = ONE cache line)

// Lane-major fragment-packed weights: fragment f = 64 lanes x 8 bf16, stored
// wp[f*512 + lane*8]. W1/W2 k-order is PERMUTED by sigma(ks,q,e) =
// (2ks+(e>>2))*16 + q*4 + (e&3) so that each layer's B-fragment is exactly
// the lane's OWN packed gelu outputs (D-layout -> B-layout transpose folded
// into the weight pack). This deletes the Tb LDS round-trip entirely; the
// MLP is fully register-resident (~80-110 live VGPRs) -> launch_bounds MUST
// allow >=128 VGPRs. R4 FAILURE: (512,8)/(256,8) capped at 64 VGPRs -> full
// scratch spill (FETCH 1.0 GB, WRITE 348 MB, VGPR=32). R5: (512,4)/(256,4).
#define FRAG 512                     // bf16 per fragment (64 lanes x 8)
#define W0F 10                       // L1 frags: 5 cb x 2 kslices
#define W1F 15                       // L2 frags: 5 cb x 3 kslices
#define W2F 6                        // L3 frags: 2 cb x 3 kslices
#define WPACK ((W0F + W1F + W2F) * FRAG)   // 15872 bf16 = 31744 B per set

#define AKEYS (VARS * PB)            // 24 agg keys
#define AKP   (AKEYS + 1)            // 25: bank-spread pitch
#define LKEYS (LPTS * VARS)          // 6 last keys
#define LKP   (LKEYS + 1)            // 7

typedef float f4 __attribute__((ext_vector_type(4)));
typedef short bf16x8 __attribute__((ext_vector_type(8)));

// lean inf-safe tanh-gelu: gelu = x - x*rcp(exp2(x*(A+B*x^2))+1); err ~3e-4.
__device__ __forceinline__ float gelu_f(float x) {
    float x2 = x * x;
    float s = x * __builtin_fmaf(0.1029418f, x2, 2.3022083f);
    float u = __builtin_amdgcn_exp2f(s);
    float r = __builtin_amdgcn_rcpf(u + 1.0f);
    return __builtin_fmaf(-x, r, x);
}
__device__ __forceinline__ unsigned short f2bf(float x) {
    unsigned int u = __float_as_uint(x);
    u += 0x7FFF + ((u >> 16) & 1);
    return (unsigned short)(u >> 16);
}
__device__ __forceinline__ float bf2f(unsigned short h) {
    return __uint_as_float(((unsigned int)h) << 16);
}
// packed RNE f32x2 -> bf16x2 (v_cvt_pk_bf16_f32 on gfx950)
__device__ __forceinline__ int pk2(float a, float b) {
    __hip_bfloat162 h = __float22bfloat162_rn(float2{a, b});
    int r; __builtin_memcpy(&r, &h, 4); return r;
}
__device__ __forceinline__ bf16x8 mk8(int a, int b, int c, int d) {
    int4 v = make_int4(a, b, c, d);
    bf16x8 r; __builtin_memcpy(&r, &v, 16); return r;
}

// One-time pack into lane-major fragment layout.
// W0 k-order: k 0..31 <- W0g rows 4..35 (features), k 32..35 <- rows 0..3.
// W1/W2 k-order: sigma-permuted (see header comment).
__device__ __forceinline__ void pack_weights(
    const float* __restrict__ W0g, const float* __restrict__ W1g,
    const float* __restrict__ W2g, unsigned short* __restrict__ wp, int t)
{
    for (int idx = t; idx < W0F * FRAG; idx += 256) {
        int f = idx >> 9, r = idx & 511;
        int lane = r >> 3, e = r & 7;
        int lm = lane & 15, qd = lane >> 4;
        int cb = f >> 1, ks = f & 1;
        int col = cb * 16 + lm;
        int k = ks * 32 + qd * 8 + e;
        float w = (k < 32) ? W0g[(k + 4) * D1 + col]
                           : ((k < 36) ? W0g[(k - 32) * D1 + col] : 0.0f);
        wp[idx] = f2bf(w);
    }
    for (int idx = t; idx < W1F * FRAG; idx += 256) {
        int f = idx >> 9, r = idx & 511;
        int lane = r >> 3, e = r & 7;
        int lm = lane & 15, qd = lane >> 4;
        int cb = f / 3, ks = f - cb * 3;
        int col = cb * 16 + lm;
        int blk = 2 * ks + (e >> 2);
        int srow = blk * 16 + qd * 4 + (e & 3);
        wp[W0F * FRAG + idx] = f2bf((blk < 5) ? W1g[srow * D1 + col] : 0.0f);
    }
    for (int idx = t; idx < W2F * FRAG; idx += 256) {
        int f = idx >> 9, r = idx & 511;
        int lane = r >> 3, e = r & 7;
        int lm = lane & 15, qd = lane >> 4;
        int cb = f / 3, ks = f - cb * 3;
        int col = cb * 16 + lm;
        int blk = 2 * ks + (e >> 2);
        int srow = blk * 16 + qd * 4 + (e & 3);
        wp[(W0F + W1F) * FRAG + idx] = f2bf((blk < 5) ? W2g[srow * OUTD + col] : 0.0f);
    }
}

#define MFMA16(A, B, C) __builtin_amdgcn_mfma_f32_16x16x32_bf16(A, B, C, 0, 0, 0)
#define GPACK(ACC) make_int2(pk2(gelu_f(ACC.x), gelu_f(ACC.y)), \
                             pk2(gelu_f(ACC.z), gelu_f(ACC.w)))

// Per-wave 16-row chunk MLP, activations fully in registers (no LDS staging).
// Weights from LDS (WA = Wls + lane*8). L3 output atomicAdd'd straight into
// accH[c*kp + key] (all 4 quads of a given lm share ckey). Manual unroll with
// NAMED pk regs (rule: runtime-indexed vector arrays go to scratch).
__device__ __forceinline__ void mlp_chunk(
    int4 featsi, int2 posfi,
    const unsigned short* WA, const float* bs,
    int quad, int ckey, float* accH, int kp)
{
    bf16x8 b1f0; __builtin_memcpy(&b1f0, &featsi, 16);
    int4 pv = make_int4(posfi.x, posfi.y, 0, 0);
    bf16x8 b1f1; __builtin_memcpy(&b1f1, &pv, 16);

    // ---- L1: K=64 (feats+pos+pad) -> 80, gelu, packed to k0..k4 ----
    int2 k0, k1, k2, k3, k4;
#define L1S(CB, PK) { \
    f4 acc = *(const f4*)&bs[(CB) * 16 + quad * 4]; \
    bf16x8 a0 = *(const bf16x8*)&WA[((CB) * 2 + 0) * FRAG]; \
    bf16x8 a1 = *(const bf16x8*)&WA[((CB) * 2 + 1) * FRAG]; \
    acc = MFMA16(a0, b1f0, acc); \
    acc = MFMA16(a1, b1f1, acc); \
    PK = GPACK(acc); }
    L1S(0, k0) L1S(1, k1) L1S(2, k2) L1S(3, k3) L1S(4, k4)
#undef L1S

    // ---- L2: 80(pad 96) -> 80 ; B-frags are direct pk concat (sigma pack) ----
    bf16x8 b20 = mk8(k0.x, k0.y, k1.x, k1.y);
    bf16x8 b21 = mk8(k2.x, k2.y, k3.x, k3.y);
    bf16x8 b22 = mk8(k4.x, k4.y, 0, 0);
    int2 q0, q1, q2, q3, q4;
#define L2S(CB, QK) { \
    f4 acc = *(const f4*)&bs[80 + (CB) * 16 + quad * 4]; \
    const unsigned short* wh = &WA[(W0F + (CB) * 3) * FRAG]; \
    bf16x8 h0 = *(const bf16x8*)&wh[0]; \
    bf16x8 h1 = *(const bf16x8*)&wh[FRAG]; \
    bf16x8 h2 = *(const bf16x8*)&wh[2 * FRAG]; \
    acc = MFMA16(h0, b20, acc); \
    acc = MFMA16(h1, b21, acc); \
    acc = MFMA16(h2, b22, acc); \
    QK = GPACK(acc); }
    L2S(0, q0) L2S(1, q1) L2S(2, q2) L2S(3, q3) L2S(4, q4)
#undef L2S

    // ---- L3: 80(pad 96) -> 32, atomic accumulate ----
    bf16x8 b30 = mk8(q0.x, q0.y, q1.x, q1.y);
    bf16x8 b31 = mk8(q2.x, q2.y, q3.x, q3.y);
    bf16x8 b32 = mk8(q4.x, q4.y, 0, 0);
#define L3S(CB) { \
    f4 acc = *(const f4*)&bs[160 + (CB) * 16 + quad * 4]; \
    const unsigned short* wh = &WA[(W0F + W1F + (CB) * 3) * FRAG]; \
    bf16x8 h0 = *(const bf16x8*)&wh[0]; \
    bf16x8 h1 = *(const bf16x8*)&wh[FRAG]; \
    bf16x8 h2 = *(const bf16x8*)&wh[2 * FRAG]; \
    acc = MFMA16(h0, b30, acc); \
    acc = MFMA16(h1, b31, acc); \
    acc = MFMA16(h2, b32, acc); \
    if (ckey >= 0) { \
        float* ap = accH + ((CB) * 16 + quad * 4) * kp + ckey; \
        atomicAdd(&ap[0], acc.x); \
        atomicAdd(&ap[kp], acc.y); \
        atomicAdd(&ap[2 * kp], acc.z); \
        atomicAdd(&ap[3 * kp], acc.w); \
    } }
    L3S(0) L3S(1)
#undef L3S
}

// ---- merged projection + scan + weight-pack ----
__global__ __launch_bounds__(256) void proj_scan_kernel(
    const float* __restrict__ inp, const float* __restrict__ grid_in,
    const float* __restrict__ W0, const float* __restrict__ b0,
    const float* __restrict__ W1, const float* __restrict__ b1,
    unsigned short* __restrict__ f0b, int* __restrict__ posb,
    const int* __restrict__ counts, int* __restrict__ offsets,
    const float* __restrict__ i0W0, const float* __restrict__ i0W1,
    const float* __restrict__ i0W2, unsigned short* __restrict__ wpack0,
    const float* __restrict__ i1W0, const float* __restrict__ i1W1,
    const float* __restrict__ i1W2, unsigned short* __restrict__ wpack1)
{
    const int t = threadIdx.x;
    if (blockIdx.x == 769) { pack_weights(i0W0, i0W1, i0W2, wpack0, t); return; }
    if (blockIdx.x == 770) { pack_weights(i1W0, i1W1, i1W2, wpack1, t); return; }
    if (blockIdx.x == 768) {
        __shared__ int ws2[4], wx2[4];
        const int lane = t & 63, wave = t >> 6;
        int4 a[8];
#pragma unroll
        for (int i = 0; i < 8; ++i) a[i] = ((const int4*)counts)[t * 8 + i];
        int s = 0;
#pragma unroll
        for (int i = 0; i < 8; ++i) s += a[i].x + a[i].y + a[i].z + a[i].w;
        int x = s;
#pragma unroll
        for (int d = 1; d < 64; d <<= 1) {
            int y = __shfl_up(x, d);
            if (lane >= d) x += y;
        }
        if (lane == 63) ws2[wave] = x;
        __syncthreads();
        if (t == 0) {
            wx2[0] = 0;
            wx2[1] = ws2[0];
            wx2[2] = ws2[0] + ws2[1];
            wx2[3] = ws2[0] + ws2[1] + ws2[2];
        }
        __syncthreads();
        int base = wx2[wave] + (x - s);
#pragma unroll
        for (int i = 0; i < 8; ++i) {
            int4 c = a[i];
            int4 o;
            o.x = base; base += c.x;
            o.y = base; base += c.y;
            o.z = base; base += c.z;
            o.w = base; base += c.w;
            ((int4*)offsets)[t * 8 + i] = o;
        }
        return;
    }
    __shared__ float W0s[8 * 64];
    __shared__ float W1s[64 * OUTD];
    __shared__ float xs[32 * 8];
    __shared__ float H[32 * 64];
    const int r0 = blockIdx.x * 32;
    for (int idx = t; idx < 512; idx += 256) W0s[idx] = W0[idx];
    for (int idx = t; idx < 64 * OUTD; idx += 256) W1s[idx] = W1[idx];
    xs[t] = inp[r0 * 8 + t];
    if (t < 32) {
        int row = r0 + t, n = row / 3;
        posb[n] = pk2(grid_in[2 * n], grid_in[2 * n + 1]);  // dup writes benign
    }
    __syncthreads();
#pragma unroll 1
    for (int p = 0; p < 8; ++p) {
        int o = t + 256 * p, r = o >> 6, col = o & 63;
        float s = b0[col];
#pragma unroll
        for (int k = 0; k < 8; ++k) s += xs[r * 8 + k] * W0s[k * 64 + col];
        H[o] = gelu_f(s);
    }
    __syncthreads();
#pragma unroll 1
    for (int p = 0; p < 4; ++p) {
        int o = t + 256 * p, r = o >> 5, c = o & 31;
        float s = b1[c];
#pragma unroll 8
        for (int k = 0; k < 64; ++k) s += H[r * 64 + k] * W1s[k * OUTD + c];
        int row = r0 + r;
        int n = row / 3, v = row - n * 3;
        f0b[((size_t)(v << 13) + n) * RP + c] = f2bf(s);
    }
}

// ---- edge MLP + owner-computes segment mean ----
// 8 waves x 512 thr, PB=8 -> 1024 blocks; LDS ~36KB.
// launch_bounds (512,4): 128-VGPR cap for the ~80-110-reg register-resident
// MLP -> 2 blocks/CU = 16 waves/CU. The R4 in-register chain is short
// (~1K cy/chunk), so 16 waves/CU is ample TLP; (512,8)'s 64-VGPR cap spilled.
__global__ __launch_bounds__(512, 4) void agg_kernel(
    const float* __restrict__ grid_in, const unsigned short* __restrict__ f0b,
    const int* __restrict__ posb,
    const int* __restrict__ nbr_index, const int* __restrict__ offsets,
    const int* __restrict__ counts,
    const unsigned short* __restrict__ wpack,
    const float* __restrict__ b0g, const float* __restrict__ b1g,
    const float* __restrict__ b2g,
    unsigned short* __restrict__ f1b)
{
    __shared__ __attribute__((aligned(16))) unsigned short Wls[WPACK];
    __shared__ __attribute__((aligned(16))) float bs[192];
    __shared__ __attribute__((aligned(16))) float accH[OUTD * AKP];
    __shared__ int offs[PB + 1];
    __shared__ int px2b[PB];
    __shared__ float invb[PB];

    const int t = threadIdx.x;
    const int lane = t & 63;
    const int lm = lane & 15, quad = lane >> 4;
    const int wave = t >> 6;
    const int p0 = blockIdx.x * PB;

    // stage all 31 weight fragments into LDS (31744 B)
    for (int idx = t; idx < WPACK / 8; idx += NT)
        ((int4*)Wls)[idx] = ((const int4*)wpack)[idx];
    const unsigned short* WA = Wls + lane * 8;

    for (int idx = t; idx < 192; idx += NT)
        bs[idx] = (idx < 80) ? b0g[idx] : (idx < 160 ? b1g[idx - 80] : b2g[idx - 160]);
    if (t < PB) {
        offs[t] = offsets[p0 + t];
        int c = counts[p0 + t];
        invb[t] = 1.0f / (float)(c > 1 ? c : 1);
        px2b[t] = pk2(grid_in[2 * (p0 + t)], grid_in[2 * (p0 + t) + 1]);
    }
    if (t == PB) offs[PB] = offsets[p0 + PB - 1] + counts[p0 + PB - 1];
    for (int idx = t; idx < OUTD * AKP; idx += NT) accH[idx] = 0.0f;
    __syncthreads();

    const int e0 = offs[0];
    const int cntT = offs[PB] - e0;
    const int Rb = VARS * cntT;
    const int nch = (Rb + 15) >> 4;

    // stage A: index fetch (key + nbr j) — one coalesced global load
    auto fetch_index = [&](int ch2, int& key, int& j) {
        key = -1; j = 0;
        if (ch2 < nch) {
            int myrow = (ch2 << 4) + lm;
            if (myrow < Rb) {
                int myv = (myrow >= 2 * cntT) ? 2 : ((myrow >= cntT) ? 1 : 0);
                int e = e0 + myrow - myv * cntT;
                int lp = 0;
#pragma unroll
                for (int l = 1; l < PB; ++l) lp += (e >= offs[l]);
                key = myv * PB + lp;
                j = nbr_index[e];
            }
        }
    };
    // stage B: record gather — j resident (loaded 1 iteration earlier)
    auto fetch_record = [&](int key, int j, int4& feats, int2& posf) {
        feats = make_int4(0, 0, 0, 0); posf = make_int2(0, 0);
        if (key >= 0) {
            int v = key >> 3, lp = key & 7;   // PB == 8
            feats = ((const int4*)(f0b + ((size_t)(v << 13) + j) * RP))[quad];
            if (quad == 0) posf = make_int2(posb[j], px2b[lp]);
        }
    };

    int keyA, jA, keyB, jB;
    fetch_index(wave, keyA, jA);
    fetch_index(wave + NWAVES, keyB, jB);
    int4 featsA; int2 posfA;
    fetch_record(keyA, jA, featsA, posfA);

    for (int ch = wave; ch < nch; ch += NWAVES) {
        int ckey = keyA; int4 cf = featsA; int2 cp = posfA;
        keyA = keyB; jA = jB;
        fetch_index(ch + 2 * NWAVES, keyB, jB);       // index 2 ahead
        fetch_record(keyA, jA, featsA, posfA);        // record 1 ahead
        mlp_chunk(cf, cp, WA, bs, quad, ckey, accH, AKP);
    }
    __syncthreads();
    for (int idx = t; idx < VARS * PB * OUTD; idx += NT) {
        int key = idx >> 5, c = idx & 31;
        int v = key >> 3, lp = key & 7;     // PB == 8
        size_t rec = ((size_t)(v << 13) + p0 + lp) * RP;
        float val = accH[c * AKP + key] * invb[lp] + bf2f(f0b[rec + c]);
        f1b[rec + c] = f2bf(val);
    }
}

// ---- kNN MLP + mean over K ----
// 256 thr / 4 waves, LPTS=2 -> 1024 blocks. launch_bounds (256,4):
// 128-VGPR cap (R4's (256,8)=64-cap spilled), 4 blocks/CU = 16 waves/CU.
__global__ __launch_bounds__(256, 4) void last_kernel(
    const unsigned short* __restrict__ f1b, const int* __restrict__ posb,
    const float* __restrict__ grid_out,
    const int* __restrict__ nbr_last,
    const unsigned short* __restrict__ wpack,
    const float* __restrict__ b0g, const float* __restrict__ b1g,
    const float* __restrict__ b2g,
    float* __restrict__ out)
{
    __shared__ __attribute__((aligned(16))) unsigned short Wls[WPACK];
    __shared__ __attribute__((aligned(16))) float bs[192];
    __shared__ __attribute__((aligned(16))) float accH[OUTD * LKP];
    __shared__ int pxo2b[LPTS];

    const int t = threadIdx.x;
    const int lane = t & 63;
    const int lm = lane & 15, quad = lane >> 4;
    const int wave = t >> 6;
    const int m0 = blockIdx.x * LPTS;

    for (int idx = t; idx < WPACK / 8; idx += NTL)
        ((int4*)Wls)[idx] = ((const int4*)wpack)[idx];
    const unsigned short* WA = Wls + lane * 8;

    for (int idx = t; idx < 192; idx += NTL)
        bs[idx] = (idx < 80) ? b0g[idx] : (idx < 160 ? b1g[idx - 80] : b2g[idx - 160]);
    if (t < LPTS)
        pxo2b[t] = pk2(grid_out[2 * (m0 + t)], grid_out[2 * (m0 + t) + 1]);
    for (int idx = t; idx < OUTD * LKP; idx += NTL) accH[idx] = 0.0f;
    __syncthreads();

    const int Rb = LPTS * VARS * KLAST;   // 60
    const int nch = (Rb + 15) >> 4;       // 4

    auto fetch_index = [&](int ch2, int& key, int& j) {
        key = -1; j = 0;
        if (ch2 < nch) {
            int myrow = (ch2 << 4) + lm;
            if (myrow < Rb) {
                int lp = myrow / 30, rr = myrow - lp * 30;
                int v = rr / KLAST, kk = rr - v * KLAST;
                j = nbr_last[(m0 + lp) * KLAST + kk];
                key = lp * VARS + v;
            }
        }
    };
    auto fetch_record = [&](int key, int j, int4& feats, int2& posf) {
        feats = make_int4(0, 0, 0, 0); posf = make_int2(0, 0);
        if (key >= 0) {
            int lp = key / VARS, v = key - lp * VARS;
            feats = ((const int4*)(f1b + ((size_t)(v << 13) + j) * RP))[quad];
            if (quad == 0) posf = make_int2(posb[j], pxo2b[lp]);
        }
    };

    int keyA, jA, keyB, jB;
    fetch_index(wave, keyA, jA);
    fetch_index(wave + NWL, keyB, jB);
    int4 featsA; int2 posfA;
    fetch_record(keyA, jA, featsA, posfA);

    for (int ch = wave; ch < nch; ch += NWL) {
        int ckey = keyA; int4 cf = featsA; int2 cp = posfA;
        keyA = keyB; jA = jB;
        fetch_index(ch + 2 * NWL, keyB, jB);
        fetch_record(keyA, jA, featsA, posfA);
        mlp_chunk(cf, cp, WA, bs, quad, ckey, accH, LKP);
    }
    __syncthreads();
    for (int idx = t; idx < LPTS * VARS * OUTD; idx += NTL) {
        int key = idx >> 5, c = idx & 31;
        int lp = key / VARS, v = key - lp * VARS;
        out[((size_t)(m0 + lp) * VARS + v) * OUTD + c] =
            accH[c * LKP + key] * (1.0f / KLAST);
    }
}

extern "C" void kernel_launch(void* const* d_in, const int* in_sizes, int n_in,
                              void* d_out, int out_size, void* d_ws, size_t ws_size,
                              hipStream_t stream) {
    const float* inp      = (const float*)d_in[0];
    const float* grid_in  = (const float*)d_in[1];
    const float* grid_out = (const float*)d_in[2];
    const float* pW0 = (const float*)d_in[3];
    const float* pb0 = (const float*)d_in[4];
    const float* pW1 = (const float*)d_in[5];
    const float* pb1 = (const float*)d_in[6];
    const float* i0W0 = (const float*)d_in[7];
    const float* i0b0 = (const float*)d_in[8];
    const float* i0W1 = (const float*)d_in[9];
    const float* i0b1 = (const float*)d_in[10];
    const float* i0W2 = (const float*)d_in[11];
    const float* i0b2 = (const float*)d_in[12];
    const float* i1W0 = (const float*)d_in[13];
    const float* i1b0 = (const float*)d_in[14];
    const float* i1W1 = (const float*)d_in[15];
    const float* i1b1 = (const float*)d_in[16];
    const float* i1W2 = (const float*)d_in[17];
    const float* i1b2 = (const float*)d_in[18];
    const int* nbr_index  = (const int*)d_in[19];
    const int* nbr_counts = (const int*)d_in[21];
    const int* nbr_last   = (const int*)d_in[22];

    unsigned short* f0b = (unsigned short*)d_ws;                      // 3*8192*32 bf16
    unsigned short* f1b = f0b + (size_t)VARS * N_PTS * RP;            // 3*8192*32 bf16
    int* offsets = (int*)(f1b + (size_t)VARS * N_PTS * RP);           // N ints
    int* posb    = offsets + N_PTS;                                   // N ints (bf16x2)
    unsigned short* wpack0 = (unsigned short*)(posb + N_PTS);         // 15872 bf16
    unsigned short* wpack1 = wpack0 + WPACK;                          // 15872 bf16

    proj_scan_kernel<<<771, 256, 0, stream>>>(inp, grid_in, pW0, pb0, pW1, pb1,
                                              f0b, posb, nbr_counts, offsets,
                                              i0W0, i0W1, i0W2, wpack0,
                                              i1W0, i1W1, i1W2, wpack1);
    agg_kernel<<<N_PTS / PB, NT, 0, stream>>>(grid_in, f0b, posb, nbr_index, offsets,
                                              nbr_counts, wpack0,
                                              i0b0, i0b1, i0b2, f1b);
    last_kernel<<<M_PTS / LPTS, NTL, 0, stream>>>(f1b, posb, grid_out, nbr_last, wpack1,
                                                  i1b0, i1b1, i1b2,
                                                  (float*)d_out);
}

// Round 6
// 332.797 us; speedup vs baseline: 1.7337x; 1.1236x over previous
//
#include <hip/hip_runtime.h>
#include <hip/hip_bf16.h>
#include <math.h>

#define N_PTS 8192
#define M_PTS 2048
#define KLAST 10
#define VARS 3
#define OUTD 32
#define D1 80
#define D2 80
#define PB 8          // points per agg block -> 1024 blocks
#define LPTS 2        // output points per last block -> 1024 blocks
#define NT 512        // agg: 8 waves per block
#define NWAVES 8
#define NTL 256       // last: 4 waves per block
#define NWL 4
#define RP 32         // f0b/f1b record pitch in bf16 (64 B = ONE cache line)

// Lane-major fragment-packed weights: fragment f = 64 lanes x 8 bf16, stored
// wp[f*512 + lane*8]. W1/W2 k-order is PERMUTED by sigma(ks,q,e) =
// (2ks+(e>>2))*16 + q*4 + (e&3) so that each layer's B-fragment is exactly
// the lane's OWN packed gelu outputs (D-layout -> B-layout transpose folded
// into the weight pack). This deletes the Tb LDS round-trip entirely; the
// MLP is fully register-resident (~90-110 live VGPRs).
// VGPR-cap calibration (measured THIS session): arch-VGPR cap = 256/min_waves
//   (512,8)->32 VGPR [R4: 1.0GB spill]   (512,4)->64 VGPR [R5: 0.6GB spill]
//   => (512,2)/(256,2) -> 128 VGPR cap, fits the ~110-reg live set.
// Occupancy comes from ACTUAL allocation (~112 -> 4 waves/SIMD = 16/CU).
#define FRAG 512                     // bf16 per fragment (64 lanes x 8)
#define W0F 10                       // L1 frags: 5 cb x 2 kslices
#define W1F 15                       // L2 frags: 5 cb x 3 kslices
#define W2F 6                        // L3 frags: 2 cb x 3 kslices
#define WPACK ((W0F + W1F + W2F) * FRAG)   // 15872 bf16 = 31744 B per set

#define AKEYS (VARS * PB)            // 24 agg keys
#define AKP   (AKEYS + 1)            // 25: bank-spread pitch
#define LKEYS (LPTS * VARS)          // 6 last keys
#define LKP   (LKEYS + 1)            // 7

typedef float f4 __attribute__((ext_vector_type(4)));
typedef short bf16x8 __attribute__((ext_vector_type(8)));

// lean inf-safe tanh-gelu: gelu = x - x*rcp(exp2(x*(A+B*x^2))+1); err ~3e-4.
__device__ __forceinline__ float gelu_f(float x) {
    float x2 = x * x;
    float s = x * __builtin_fmaf(0.1029418f, x2, 2.3022083f);
    float u = __builtin_amdgcn_exp2f(s);
    float r = __builtin_amdgcn_rcpf(u + 1.0f);
    return __builtin_fmaf(-x, r, x);
}
__device__ __forceinline__ unsigned short f2bf(float x) {
    unsigned int u = __float_as_uint(x);
    u += 0x7FFF + ((u >> 16) & 1);
    return (unsigned short)(u >> 16);
}
__device__ __forceinline__ float bf2f(unsigned short h) {
    return __uint_as_float(((unsigned int)h) << 16);
}
// packed RNE f32x2 -> bf16x2 (v_cvt_pk_bf16_f32 on gfx950)
__device__ __forceinline__ int pk2(float a, float b) {
    __hip_bfloat162 h = __float22bfloat162_rn(float2{a, b});
    int r; __builtin_memcpy(&r, &h, 4); return r;
}
__device__ __forceinline__ bf16x8 mk8(int a, int b, int c, int d) {
    int4 v = make_int4(a, b, c, d);
    bf16x8 r; __builtin_memcpy(&r, &v, 16); return r;
}

// One-time pack into lane-major fragment layout.
// W0 k-order: k 0..31 <- W0g rows 4..35 (features), k 32..35 <- rows 0..3.
// W1/W2 k-order: sigma-permuted (see header comment).
__device__ __forceinline__ void pack_weights(
    const float* __restrict__ W0g, const float* __restrict__ W1g,
    const float* __restrict__ W2g, unsigned short* __restrict__ wp, int t)
{
    for (int idx = t; idx < W0F * FRAG; idx += 256) {
        int f = idx >> 9, r = idx & 511;
        int lane = r >> 3, e = r & 7;
        int lm = lane & 15, qd = lane >> 4;
        int cb = f >> 1, ks = f & 1;
        int col = cb * 16 + lm;
        int k = ks * 32 + qd * 8 + e;
        float w = (k < 32) ? W0g[(k + 4) * D1 + col]
                           : ((k < 36) ? W0g[(k - 32) * D1 + col] : 0.0f);
        wp[idx] = f2bf(w);
    }
    for (int idx = t; idx < W1F * FRAG; idx += 256) {
        int f = idx >> 9, r = idx & 511;
        int lane = r >> 3, e = r & 7;
        int lm = lane & 15, qd = lane >> 4;
        int cb = f / 3, ks = f - cb * 3;
        int col = cb * 16 + lm;
        int blk = 2 * ks + (e >> 2);
        int srow = blk * 16 + qd * 4 + (e & 3);
        wp[W0F * FRAG + idx] = f2bf((blk < 5) ? W1g[srow * D1 + col] : 0.0f);
    }
    for (int idx = t; idx < W2F * FRAG; idx += 256) {
        int f = idx >> 9, r = idx & 511;
        int lane = r >> 3, e = r & 7;
        int lm = lane & 15, qd = lane >> 4;
        int cb = f / 3, ks = f - cb * 3;
        int col = cb * 16 + lm;
        int blk = 2 * ks + (e >> 2);
        int srow = blk * 16 + qd * 4 + (e & 3);
        wp[(W0F + W1F) * FRAG + idx] = f2bf((blk < 5) ? W2g[srow * OUTD + col] : 0.0f);
    }
}

#define MFMA16(A, B, C) __builtin_amdgcn_mfma_f32_16x16x32_bf16(A, B, C, 0, 0, 0)
#define GPACK(ACC) make_int2(pk2(gelu_f(ACC.x), gelu_f(ACC.y)), \
                             pk2(gelu_f(ACC.z), gelu_f(ACC.w)))

// Per-wave 16-row chunk MLP, activations fully in registers (no LDS staging).
// Weights from LDS (WA = Wls + lane*8). L3 output atomicAdd'd straight into
// accH[c*kp + key] (all 4 quads of a given lm share ckey). Manual unroll with
// NAMED pk regs (rule: runtime-indexed vector arrays go to scratch).
__device__ __forceinline__ void mlp_chunk(
    int4 featsi, int2 posfi,
    const unsigned short* WA, const float* bs,
    int quad, int ckey, float* accH, int kp)
{
    bf16x8 b1f0; __builtin_memcpy(&b1f0, &featsi, 16);
    int4 pv = make_int4(posfi.x, posfi.y, 0, 0);
    bf16x8 b1f1; __builtin_memcpy(&b1f1, &pv, 16);

    // ---- L1: K=64 (feats+pos+pad) -> 80, gelu, packed to k0..k4 ----
    int2 k0, k1, k2, k3, k4;
#define L1S(CB, PK) { \
    f4 acc = *(const f4*)&bs[(CB) * 16 + quad * 4]; \
    bf16x8 a0 = *(const bf16x8*)&WA[((CB) * 2 + 0) * FRAG]; \
    bf16x8 a1 = *(const bf16x8*)&WA[((CB) * 2 + 1) * FRAG]; \
    acc = MFMA16(a0, b1f0, acc); \
    acc = MFMA16(a1, b1f1, acc); \
    PK = GPACK(acc); }
    L1S(0, k0) L1S(1, k1) L1S(2, k2) L1S(3, k3) L1S(4, k4)
#undef L1S

    // ---- L2: 80(pad 96) -> 80 ; B-frags are direct pk concat (sigma pack) ----
    bf16x8 b20 = mk8(k0.x, k0.y, k1.x, k1.y);
    bf16x8 b21 = mk8(k2.x, k2.y, k3.x, k3.y);
    bf16x8 b22 = mk8(k4.x, k4.y, 0, 0);
    int2 q0, q1, q2, q3, q4;
#define L2S(CB, QK) { \
    f4 acc = *(const f4*)&bs[80 + (CB) * 16 + quad * 4]; \
    const unsigned short* wh = &WA[(W0F + (CB) * 3) * FRAG]; \
    bf16x8 h0 = *(const bf16x8*)&wh[0]; \
    bf16x8 h1 = *(const bf16x8*)&wh[FRAG]; \
    bf16x8 h2 = *(const bf16x8*)&wh[2 * FRAG]; \
    acc = MFMA16(h0, b20, acc); \
    acc = MFMA16(h1, b21, acc); \
    acc = MFMA16(h2, b22, acc); \
    QK = GPACK(acc); }
    L2S(0, q0) L2S(1, q1) L2S(2, q2) L2S(3, q3) L2S(4, q4)
#undef L2S

    // ---- L3: 80(pad 96) -> 32, atomic accumulate ----
    bf16x8 b30 = mk8(q0.x, q0.y, q1.x, q1.y);
    bf16x8 b31 = mk8(q2.x, q2.y, q3.x, q3.y);
    bf16x8 b32 = mk8(q4.x, q4.y, 0, 0);
#define L3S(CB) { \
    f4 acc = *(const f4*)&bs[160 + (CB) * 16 + quad * 4]; \
    const unsigned short* wh = &WA[(W0F + W1F + (CB) * 3) * FRAG]; \
    bf16x8 h0 = *(const bf16x8*)&wh[0]; \
    bf16x8 h1 = *(const bf16x8*)&wh[FRAG]; \
    bf16x8 h2 = *(const bf16x8*)&wh[2 * FRAG]; \
    acc = MFMA16(h0, b30, acc); \
    acc = MFMA16(h1, b31, acc); \
    acc = MFMA16(h2, b32, acc); \
    if (ckey >= 0) { \
        float* ap = accH + ((CB) * 16 + quad * 4) * kp + ckey; \
        atomicAdd(&ap[0], acc.x); \
        atomicAdd(&ap[kp], acc.y); \
        atomicAdd(&ap[2 * kp], acc.z); \
        atomicAdd(&ap[3 * kp], acc.w); \
    } }
    L3S(0) L3S(1)
#undef L3S
}

// ---- merged projection + scan + weight-pack ----
__global__ __launch_bounds__(256) void proj_scan_kernel(
    const float* __restrict__ inp, const float* __restrict__ grid_in,
    const float* __restrict__ W0, const float* __restrict__ b0,
    const float* __restrict__ W1, const float* __restrict__ b1,
    unsigned short* __restrict__ f0b, int* __restrict__ posb,
    const int* __restrict__ counts, int* __restrict__ offsets,
    const float* __restrict__ i0W0, const float* __restrict__ i0W1,
    const float* __restrict__ i0W2, unsigned short* __restrict__ wpack0,
    const float* __restrict__ i1W0, const float* __restrict__ i1W1,
    const float* __restrict__ i1W2, unsigned short* __restrict__ wpack1)
{
    const int t = threadIdx.x;
    if (blockIdx.x == 769) { pack_weights(i0W0, i0W1, i0W2, wpack0, t); return; }
    if (blockIdx.x == 770) { pack_weights(i1W0, i1W1, i1W2, wpack1, t); return; }
    if (blockIdx.x == 768) {
        __shared__ int ws2[4], wx2[4];
        const int lane = t & 63, wave = t >> 6;
        int4 a[8];
#pragma unroll
        for (int i = 0; i < 8; ++i) a[i] = ((const int4*)counts)[t * 8 + i];
        int s = 0;
#pragma unroll
        for (int i = 0; i < 8; ++i) s += a[i].x + a[i].y + a[i].z + a[i].w;
        int x = s;
#pragma unroll
        for (int d = 1; d < 64; d <<= 1) {
            int y = __shfl_up(x, d);
            if (lane >= d) x += y;
        }
        if (lane == 63) ws2[wave] = x;
        __syncthreads();
        if (t == 0) {
            wx2[0] = 0;
            wx2[1] = ws2[0];
            wx2[2] = ws2[0] + ws2[1];
            wx2[3] = ws2[0] + ws2[1] + ws2[2];
        }
        __syncthreads();
        int base = wx2[wave] + (x - s);
#pragma unroll
        for (int i = 0; i < 8; ++i) {
            int4 c = a[i];
            int4 o;
            o.x = base; base += c.x;
            o.y = base; base += c.y;
            o.z = base; base += c.z;
            o.w = base; base += c.w;
            ((int4*)offsets)[t * 8 + i] = o;
        }
        return;
    }
    __shared__ float W0s[8 * 64];
    __shared__ float W1s[64 * OUTD];
    __shared__ float xs[32 * 8];
    __shared__ float H[32 * 64];
    const int r0 = blockIdx.x * 32;
    for (int idx = t; idx < 512; idx += 256) W0s[idx] = W0[idx];
    for (int idx = t; idx < 64 * OUTD; idx += 256) W1s[idx] = W1[idx];
    xs[t] = inp[r0 * 8 + t];
    if (t < 32) {
        int row = r0 + t, n = row / 3;
        posb[n] = pk2(grid_in[2 * n], grid_in[2 * n + 1]);  // dup writes benign
    }
    __syncthreads();
#pragma unroll 1
    for (int p = 0; p < 8; ++p) {
        int o = t + 256 * p, r = o >> 6, col = o & 63;
        float s = b0[col];
#pragma unroll
        for (int k = 0; k < 8; ++k) s += xs[r * 8 + k] * W0s[k * 64 + col];
        H[o] = gelu_f(s);
    }
    __syncthreads();
#pragma unroll 1
    for (int p = 0; p < 4; ++p) {
        int o = t + 256 * p, r = o >> 5, c = o & 31;
        float s = b1[c];
#pragma unroll 8
        for (int k = 0; k < 64; ++k) s += H[r * 64 + k] * W1s[k * OUTD + c];
        int row = r0 + r;
        int n = row / 3, v = row - n * 3;
        f0b[((size_t)(v << 13) + n) * RP + c] = f2bf(s);
    }
}

// ---- edge MLP + owner-computes segment mean ----
// 8 waves x 512 thr, PB=8 -> 1024 blocks; LDS ~36KB.
// launch_bounds (512,2): arch-VGPR cap = 256/2 = 128 (calibrated R4/R5),
// fits the ~110-reg register-resident MLP with NO spill. Runtime occupancy
// follows actual allocation (~112 regs -> 4 waves/SIMD = 16 waves/CU).
__global__ __launch_bounds__(512, 2) void agg_kernel(
    const float* __restrict__ grid_in, const unsigned short* __restrict__ f0b,
    const int* __restrict__ posb,
    const int* __restrict__ nbr_index, const int* __restrict__ offsets,
    const int* __restrict__ counts,
    const unsigned short* __restrict__ wpack,
    const float* __restrict__ b0g, const float* __restrict__ b1g,
    const float* __restrict__ b2g,
    unsigned short* __restrict__ f1b)
{
    __shared__ __attribute__((aligned(16))) unsigned short Wls[WPACK];
    __shared__ __attribute__((aligned(16))) float bs[192];
    __shared__ __attribute__((aligned(16))) float accH[OUTD * AKP];
    __shared__ int offs[PB + 1];
    __shared__ int px2b[PB];
    __shared__ float invb[PB];

    const int t = threadIdx.x;
    const int lane = t & 63;
    const int lm = lane & 15, quad = lane >> 4;
    const int wave = t >> 6;
    const int p0 = blockIdx.x * PB;

    // stage all 31 weight fragments into LDS (31744 B)
    for (int idx = t; idx < WPACK / 8; idx += NT)
        ((int4*)Wls)[idx] = ((const int4*)wpack)[idx];
    const unsigned short* WA = Wls + lane * 8;

    for (int idx = t; idx < 192; idx += NT)
        bs[idx] = (idx < 80) ? b0g[idx] : (idx < 160 ? b1g[idx - 80] : b2g[idx - 160]);
    if (t < PB) {
        offs[t] = offsets[p0 + t];
        int c = counts[p0 + t];
        invb[t] = 1.0f / (float)(c > 1 ? c : 1);
        px2b[t] = pk2(grid_in[2 * (p0 + t)], grid_in[2 * (p0 + t) + 1]);
    }
    if (t == PB) offs[PB] = offsets[p0 + PB - 1] + counts[p0 + PB - 1];
    for (int idx = t; idx < OUTD * AKP; idx += NT) accH[idx] = 0.0f;
    __syncthreads();

    const int e0 = offs[0];
    const int cntT = offs[PB] - e0;
    const int Rb = VARS * cntT;
    const int nch = (Rb + 15) >> 4;

    // stage A: index fetch (key + nbr j) — one coalesced global load
    auto fetch_index = [&](int ch2, int& key, int& j) {
        key = -1; j = 0;
        if (ch2 < nch) {
            int myrow = (ch2 << 4) + lm;
            if (myrow < Rb) {
                int myv = (myrow >= 2 * cntT) ? 2 : ((myrow >= cntT) ? 1 : 0);
                int e = e0 + myrow - myv * cntT;
                int lp = 0;
#pragma unroll
                for (int l = 1; l < PB; ++l) lp += (e >= offs[l]);
                key = myv * PB + lp;
                j = nbr_index[e];
            }
        }
    };
    // stage B: record gather — j resident (loaded 1 iteration earlier)
    auto fetch_record = [&](int key, int j, int4& feats, int2& posf) {
        feats = make_int4(0, 0, 0, 0); posf = make_int2(0, 0);
        if (key >= 0) {
            int v = key >> 3, lp = key & 7;   // PB == 8
            feats = ((const int4*)(f0b + ((size_t)(v << 13) + j) * RP))[quad];
            if (quad == 0) posf = make_int2(posb[j], px2b[lp]);
        }
    };

    int keyA, jA, keyB, jB;
    fetch_index(wave, keyA, jA);
    fetch_index(wave + NWAVES, keyB, jB);
    int4 featsA; int2 posfA;
    fetch_record(keyA, jA, featsA, posfA);

    for (int ch = wave; ch < nch; ch += NWAVES) {
        int ckey = keyA; int4 cf = featsA; int2 cp = posfA;
        keyA = keyB; jA = jB;
        fetch_index(ch + 2 * NWAVES, keyB, jB);       // index 2 ahead
        fetch_record(keyA, jA, featsA, posfA);        // record 1 ahead
        mlp_chunk(cf, cp, WA, bs, quad, ckey, accH, AKP);
    }
    __syncthreads();
    for (int idx = t; idx < VARS * PB * OUTD; idx += NT) {
        int key = idx >> 5, c = idx & 31;
        int v = key >> 3, lp = key & 7;     // PB == 8
        size_t rec = ((size_t)(v << 13) + p0 + lp) * RP;
        float val = accH[c * AKP + key] * invb[lp] + bf2f(f0b[rec + c]);
        f1b[rec + c] = f2bf(val);
    }
}

// ---- kNN MLP + mean over K ----
// 256 thr / 4 waves, LPTS=2 -> 1024 blocks. launch_bounds (256,2):
// arch-VGPR cap 128 (same calibration), no spill.
__global__ __launch_bounds__(256, 2) void last_kernel(
    const unsigned short* __restrict__ f1b, const int* __restrict__ posb,
    const float* __restrict__ grid_out,
    const int* __restrict__ nbr_last,
    const unsigned short* __restrict__ wpack,
    const float* __restrict__ b0g, const float* __restrict__ b1g,
    const float* __restrict__ b2g,
    float* __restrict__ out)
{
    __shared__ __attribute__((aligned(16))) unsigned short Wls[WPACK];
    __shared__ __attribute__((aligned(16))) float bs[192];
    __shared__ __attribute__((aligned(16))) float accH[OUTD * LKP];
    __shared__ int pxo2b[LPTS];

    const int t = threadIdx.x;
    const int lane = t & 63;
    const int lm = lane & 15, quad = lane >> 4;
    const int wave = t >> 6;
    const int m0 = blockIdx.x * LPTS;

    for (int idx = t; idx < WPACK / 8; idx += NTL)
        ((int4*)Wls)[idx] = ((const int4*)wpack)[idx];
    const unsigned short* WA = Wls + lane * 8;

    for (int idx = t; idx < 192; idx += NTL)
        bs[idx] = (idx < 80) ? b0g[idx] : (idx < 160 ? b1g[idx - 80] : b2g[idx - 160]);
    if (t < LPTS)
        pxo2b[t] = pk2(grid_out[2 * (m0 + t)], grid_out[2 * (m0 + t) + 1]);
    for (int idx = t; idx < OUTD * LKP; idx += NTL) accH[idx] = 0.0f;
    __syncthreads();

    const int Rb = LPTS * VARS * KLAST;   // 60
    const int nch = (Rb + 15) >> 4;       // 4

    auto fetch_index = [&](int ch2, int& key, int& j) {
        key = -1; j = 0;
        if (ch2 < nch) {
            int myrow = (ch2 << 4) + lm;
            if (myrow < Rb) {
                int lp = myrow / 30, rr = myrow - lp * 30;
                int v = rr / KLAST, kk = rr - v * KLAST;
                j = nbr_last[(m0 + lp) * KLAST + kk];
                key = lp * VARS + v;
            }
        }
    };
    auto fetch_record = [&](int key, int j, int4& feats, int2& posf) {
        feats = make_int4(0, 0, 0, 0); posf = make_int2(0, 0);
        if (key >= 0) {
            int lp = key / VARS, v = key - lp * VARS;
            feats = ((const int4*)(f1b + ((size_t)(v << 13) + j) * RP))[quad];
            if (quad == 0) posf = make_int2(posb[j], pxo2b[lp]);
        }
    };

    int keyA, jA, keyB, jB;
    fetch_index(wave, keyA, jA);
    fetch_index(wave + NWL, keyB, jB);
    int4 featsA; int2 posfA;
    fetch_record(keyA, jA, featsA, posfA);

    for (int ch = wave; ch < nch; ch += NWL) {
        int ckey = keyA; int4 cf = featsA; int2 cp = posfA;
        keyA = keyB; jA = jB;
        fetch_index(ch + 2 * NWL, keyB, jB);
        fetch_record(keyA, jA, featsA, posfA);
        mlp_chunk(cf, cp, WA, bs, quad, ckey, accH, LKP);
    }
    __syncthreads();
    for (int idx = t; idx < LPTS * VARS * OUTD; idx += NTL) {
        int key = idx >> 5, c = idx & 31;
        int lp = key / VARS, v = key - lp * VARS;
        out[((size_t)(m0 + lp) * VARS + v) * OUTD + c] =
            accH[c * LKP + key] * (1.0f / KLAST);
    }
}

extern "C" void kernel_launch(void* const* d_in, const int* in_sizes, int n_in,
                              void* d_out, int out_size, void* d_ws, size_t ws_size,
                              hipStream_t stream) {
    const float* inp      = (const float*)d_in[0];
    const float* grid_in  = (const float*)d_in[1];
    const float* grid_out = (const float*)d_in[2];
    const float* pW0 = (const float*)d_in[3];
    const float* pb0 = (const float*)d_in[4];
    const float* pW1 = (const float*)d_in[5];
    const float* pb1 = (const float*)d_in[6];
    const float* i0W0 = (const float*)d_in[7];
    const float* i0b0 = (const float*)d_in[8];
    const float* i0W1 = (const float*)d_in[9];
    const float* i0b1 = (const float*)d_in[10];
    const float* i0W2 = (const float*)d_in[11];
    const float* i0b2 = (const float*)d_in[12];
    const float* i1W0 = (const float*)d_in[13];
    const float* i1b0 = (const float*)d_in[14];
    const float* i1W1 = (const float*)d_in[15];
    const float* i1b1 = (const float*)d_in[16];
    const float* i1W2 = (const float*)d_in[17];
    const float* i1b2 = (const float*)d_in[18];
    const int* nbr_index  = (const int*)d_in[19];
    const int* nbr_counts = (const int*)d_in[21];
    const int* nbr_last   = (const int*)d_in[22];

    unsigned short* f0b = (unsigned short*)d_ws;                      // 3*8192*32 bf16
    unsigned short* f1b = f0b + (size_t)VARS * N_PTS * RP;            // 3*8192*32 bf16
    int* offsets = (int*)(f1b + (size_t)VARS * N_PTS * RP);           // N ints
    int* posb    = offsets + N_PTS;                                   // N ints (bf16x2)
    unsigned short* wpack0 = (unsigned short*)(posb + N_PTS);         // 15872 bf16
    unsigned short* wpack1 = wpack0 + WPACK;                          // 15872 bf16

    proj_scan_kernel<<<771, 256, 0, stream>>>(inp, grid_in, pW0, pb0, pW1, pb1,
                                              f0b, posb, nbr_counts, offsets,
                                              i0W0, i0W1, i0W2, wpack0,
                                              i1W0, i1W1, i1W2, wpack1);
    agg_kernel<<<N_PTS / PB, NT, 0, stream>>>(grid_in, f0b, posb, nbr_index, offsets,
                                              nbr_counts, wpack0,
                                              i0b0, i0b1, i0b2, f1b);
    last_kernel<<<M_PTS / LPTS, NTL, 0, stream>>>(f1b, posb, grid_out, nbr_last, wpack1,
                                                  i1b0, i1b1, i1b2,
                                                  (float*)d_out);
}

// Round 7
// 327.187 us; speedup vs baseline: 1.7634x; 1.0171x over previous
//
#include <hip/hip_runtime.h>
#include <hip/hip_bf16.h>
#include <math.h>

#define N_PTS 8192
#define M_PTS 2048
#define KLAST 10
#define VARS 3
#define OUTD 32
#define D1 80
#define D2 80
#define PB 4          // points per agg block -> 2048 blocks of 4 waves
#define LPTS 2        // output points per last block -> 1024 blocks
#define NT 256        // agg: 4 waves per block (occupancy de-quantization, R7)
#define NWAVES 4
#define NTL 256       // last: 4 waves per block
#define NWL 4
#define RP 32         // f0b/f1b record pitch in bf16 (64 B = ONE cache line)

// Lane-major fragment-packed weights: fragment f = 64 lanes x 8 bf16, stored
// wp[f*512 + lane*8]. W1/W2 k-order PERMUTED by sigma(ks,q,e) =
// (2ks+(e>>2))*16 + q*4 + (e&3): each layer's B-fragment is the lane's OWN
// packed gelu outputs (D->B transpose folded into the pack). MLP is fully
// register-resident; weights read from LDS.
// R6 RESULT: no spill (FETCH 7MB), VGPR=116, bank-conflicts 0 — but
// Occupancy 21% (~1.7 waves/SIMD): with 8-wave blocks residency quantizes to
// whole blocks and the unified VGPR+AGPR footprint pushed past the 2-block
// threshold -> 1 block/CU, VALUBusy 20.7% ~= ONE wave's duty. R7: 4-wave
// blocks (NT=256, PB=4) so each resident block adds 1 wave/SIMD; bounds stay
// (256,2) = 128 arch-VGPR cap (calibrated R4/R5: cap = 256/min_waves).
#define FRAG 512                     // bf16 per fragment (64 lanes x 8)
#define W0F 10                       // L1 frags: 5 cb x 2 kslices
#define W1F 15                       // L2 frags: 5 cb x 3 kslices
#define W2F 6                        // L3 frags: 2 cb x 3 kslices
#define WPACK ((W0F + W1F + W2F) * FRAG)   // 15872 bf16 = 31744 B per set

#define AKEYS (VARS * PB)            // 12 agg keys
#define AKP   (AKEYS + 1)            // 13: bank-spread pitch
#define LKEYS (LPTS * VARS)          // 6 last keys
#define LKP   (LKEYS + 1)            // 7

typedef float f4 __attribute__((ext_vector_type(4)));
typedef short bf16x8 __attribute__((ext_vector_type(8)));

// lean inf-safe tanh-gelu: gelu = x - x*rcp(exp2(x*(A+B*x^2))+1); err ~3e-4.
__device__ __forceinline__ float gelu_f(float x) {
    float x2 = x * x;
    float s = x * __builtin_fmaf(0.1029418f, x2, 2.3022083f);
    float u = __builtin_amdgcn_exp2f(s);
    float r = __builtin_amdgcn_rcpf(u + 1.0f);
    return __builtin_fmaf(-x, r, x);
}
__device__ __forceinline__ unsigned short f2bf(float x) {
    unsigned int u = __float_as_uint(x);
    u += 0x7FFF + ((u >> 16) & 1);
    return (unsigned short)(u >> 16);
}
__device__ __forceinline__ float bf2f(unsigned short h) {
    return __uint_as_float(((unsigned int)h) << 16);
}
// packed RNE f32x2 -> bf16x2 (v_cvt_pk_bf16_f32 on gfx950)
__device__ __forceinline__ int pk2(float a, float b) {
    __hip_bfloat162 h = __float22bfloat162_rn(float2{a, b});
    int r; __builtin_memcpy(&r, &h, 4); return r;
}
__device__ __forceinline__ bf16x8 mk8(int a, int b, int c, int d) {
    int4 v = make_int4(a, b, c, d);
    bf16x8 r; __builtin_memcpy(&r, &v, 16); return r;
}

// One-time pack into lane-major fragment layout.
// W0 k-order: k 0..31 <- W0g rows 4..35 (features), k 32..35 <- rows 0..3.
// W1/W2 k-order: sigma-permuted (see header comment).
__device__ __forceinline__ void pack_weights(
    const float* __restrict__ W0g, const float* __restrict__ W1g,
    const float* __restrict__ W2g, unsigned short* __restrict__ wp, int t)
{
    for (int idx = t; idx < W0F * FRAG; idx += 256) {
        int f = idx >> 9, r = idx & 511;
        int lane = r >> 3, e = r & 7;
        int lm = lane & 15, qd = lane >> 4;
        int cb = f >> 1, ks = f & 1;
        int col = cb * 16 + lm;
        int k = ks * 32 + qd * 8 + e;
        float w = (k < 32) ? W0g[(k + 4) * D1 + col]
                           : ((k < 36) ? W0g[(k - 32) * D1 + col] : 0.0f);
        wp[idx] = f2bf(w);
    }
    for (int idx = t; idx < W1F * FRAG; idx += 256) {
        int f = idx >> 9, r = idx & 511;
        int lane = r >> 3, e = r & 7;
        int lm = lane & 15, qd = lane >> 4;
        int cb = f / 3, ks = f - cb * 3;
        int col = cb * 16 + lm;
        int blk = 2 * ks + (e >> 2);
        int srow = blk * 16 + qd * 4 + (e & 3);
        wp[W0F * FRAG + idx] = f2bf((blk < 5) ? W1g[srow * D1 + col] : 0.0f);
    }
    for (int idx = t; idx < W2F * FRAG; idx += 256) {
        int f = idx >> 9, r = idx & 511;
        int lane = r >> 3, e = r & 7;
        int lm = lane & 15, qd = lane >> 4;
        int cb = f / 3, ks = f - cb * 3;
        int col = cb * 16 + lm;
        int blk = 2 * ks + (e >> 2);
        int srow = blk * 16 + qd * 4 + (e & 3);
        wp[(W0F + W1F) * FRAG + idx] = f2bf((blk < 5) ? W2g[srow * OUTD + col] : 0.0f);
    }
}

#define MFMA16(A, B, C) __builtin_amdgcn_mfma_f32_16x16x32_bf16(A, B, C, 0, 0, 0)
#define GPACK(ACC) make_int2(pk2(gelu_f(ACC.x), gelu_f(ACC.y)), \
                             pk2(gelu_f(ACC.z), gelu_f(ACC.w)))

// Per-wave 16-row chunk MLP, activations fully in registers (no LDS staging).
// Weights from LDS (WA = Wls + lane*8). L3 output atomicAdd'd straight into
// accH[c*kp + key] (all 4 quads of a given lm share ckey). Manual unroll with
// NAMED pk regs (rule: runtime-indexed vector arrays go to scratch).
__device__ __forceinline__ void mlp_chunk(
    int4 featsi, int2 posfi,
    const unsigned short* WA, const float* bs,
    int quad, int ckey, float* accH, int kp)
{
    bf16x8 b1f0; __builtin_memcpy(&b1f0, &featsi, 16);
    int4 pv = make_int4(posfi.x, posfi.y, 0, 0);
    bf16x8 b1f1; __builtin_memcpy(&b1f1, &pv, 16);

    // ---- L1: K=64 (feats+pos+pad) -> 80, gelu, packed to k0..k4 ----
    int2 k0, k1, k2, k3, k4;
#define L1S(CB, PK) { \
    f4 acc = *(const f4*)&bs[(CB) * 16 + quad * 4]; \
    bf16x8 a0 = *(const bf16x8*)&WA[((CB) * 2 + 0) * FRAG]; \
    bf16x8 a1 = *(const bf16x8*)&WA[((CB) * 2 + 1) * FRAG]; \
    acc = MFMA16(a0, b1f0, acc); \
    acc = MFMA16(a1, b1f1, acc); \
    PK = GPACK(acc); }
    L1S(0, k0) L1S(1, k1) L1S(2, k2) L1S(3, k3) L1S(4, k4)
#undef L1S

    // ---- L2: 80(pad 96) -> 80 ; B-frags are direct pk concat (sigma pack) ----
    bf16x8 b20 = mk8(k0.x, k0.y, k1.x, k1.y);
    bf16x8 b21 = mk8(k2.x, k2.y, k3.x, k3.y);
    bf16x8 b22 = mk8(k4.x, k4.y, 0, 0);
    int2 q0, q1, q2, q3, q4;
#define L2S(CB, QK) { \
    f4 acc = *(const f4*)&bs[80 + (CB) * 16 + quad * 4]; \
    const unsigned short* wh = &WA[(W0F + (CB) * 3) * FRAG]; \
    bf16x8 h0 = *(const bf16x8*)&wh[0]; \
    bf16x8 h1 = *(const bf16x8*)&wh[FRAG]; \
    bf16x8 h2 = *(const bf16x8*)&wh[2 * FRAG]; \
    acc = MFMA16(h0, b20, acc); \
    acc = MFMA16(h1, b21, acc); \
    acc = MFMA16(h2, b22, acc); \
    QK = GPACK(acc); }
    L2S(0, q0) L2S(1, q1) L2S(2, q2) L2S(3, q3) L2S(4, q4)
#undef L2S

    // ---- L3: 80(pad 96) -> 32, atomic accumulate ----
    bf16x8 b30 = mk8(q0.x, q0.y, q1.x, q1.y);
    bf16x8 b31 = mk8(q2.x, q2.y, q3.x, q3.y);
    bf16x8 b32 = mk8(q4.x, q4.y, 0, 0);
#define L3S(CB) { \
    f4 acc = *(const f4*)&bs[160 + (CB) * 16 + quad * 4]; \
    const unsigned short* wh = &WA[(W0F + W1F + (CB) * 3) * FRAG]; \
    bf16x8 h0 = *(const bf16x8*)&wh[0]; \
    bf16x8 h1 = *(const bf16x8*)&wh[FRAG]; \
    bf16x8 h2 = *(const bf16x8*)&wh[2 * FRAG]; \
    acc = MFMA16(h0, b30, acc); \
    acc = MFMA16(h1, b31, acc); \
    acc = MFMA16(h2, b32, acc); \
    if (ckey >= 0) { \
        float* ap = accH + ((CB) * 16 + quad * 4) * kp + ckey; \
        atomicAdd(&ap[0], acc.x); \
        atomicAdd(&ap[kp], acc.y); \
        atomicAdd(&ap[2 * kp], acc.z); \
        atomicAdd(&ap[3 * kp], acc.w); \
    } }
    L3S(0) L3S(1)
#undef L3S
}

// ---- merged projection + scan + weight-pack ----
__global__ __launch_bounds__(256) void proj_scan_kernel(
    const float* __restrict__ inp, const float* __restrict__ grid_in,
    const float* __restrict__ W0, const float* __restrict__ b0,
    const float* __restrict__ W1, const float* __restrict__ b1,
    unsigned short* __restrict__ f0b, int* __restrict__ posb,
    const int* __restrict__ counts, int* __restrict__ offsets,
    const float* __restrict__ i0W0, const float* __restrict__ i0W1,
    const float* __restrict__ i0W2, unsigned short* __restrict__ wpack0,
    const float* __restrict__ i1W0, const float* __restrict__ i1W1,
    const float* __restrict__ i1W2, unsigned short* __restrict__ wpack1)
{
    const int t = threadIdx.x;
    if (blockIdx.x == 769) { pack_weights(i0W0, i0W1, i0W2, wpack0, t); return; }
    if (blockIdx.x == 770) { pack_weights(i1W0, i1W1, i1W2, wpack1, t); return; }
    if (blockIdx.x == 768) {
        __shared__ int ws2[4], wx2[4];
        const int lane = t & 63, wave = t >> 6;
        int4 a[8];
#pragma unroll
        for (int i = 0; i < 8; ++i) a[i] = ((const int4*)counts)[t * 8 + i];
        int s = 0;
#pragma unroll
        for (int i = 0; i < 8; ++i) s += a[i].x + a[i].y + a[i].z + a[i].w;
        int x = s;
#pragma unroll
        for (int d = 1; d < 64; d <<= 1) {
            int y = __shfl_up(x, d);
            if (lane >= d) x += y;
        }
        if (lane == 63) ws2[wave] = x;
        __syncthreads();
        if (t == 0) {
            wx2[0] = 0;
            wx2[1] = ws2[0];
            wx2[2] = ws2[0] + ws2[1];
            wx2[3] = ws2[0] + ws2[1] + ws2[2];
        }
        __syncthreads();
        int base = wx2[wave] + (x - s);
#pragma unroll
        for (int i = 0; i < 8; ++i) {
            int4 c = a[i];
            int4 o;
            o.x = base; base += c.x;
            o.y = base; base += c.y;
            o.z = base; base += c.z;
            o.w = base; base += c.w;
            ((int4*)offsets)[t * 8 + i] = o;
        }
        return;
    }
    __shared__ float W0s[8 * 64];
    __shared__ float W1s[64 * OUTD];
    __shared__ float xs[32 * 8];
    __shared__ float H[32 * 64];
    const int r0 = blockIdx.x * 32;
    for (int idx = t; idx < 512; idx += 256) W0s[idx] = W0[idx];
    for (int idx = t; idx < 64 * OUTD; idx += 256) W1s[idx] = W1[idx];
    xs[t] = inp[r0 * 8 + t];
    if (t < 32) {
        int row = r0 + t, n = row / 3;
        posb[n] = pk2(grid_in[2 * n], grid_in[2 * n + 1]);  // dup writes benign
    }
    __syncthreads();
#pragma unroll 1
    for (int p = 0; p < 8; ++p) {
        int o = t + 256 * p, r = o >> 6, col = o & 63;
        float s = b0[col];
#pragma unroll
        for (int k = 0; k < 8; ++k) s += xs[r * 8 + k] * W0s[k * 64 + col];
        H[o] = gelu_f(s);
    }
    __syncthreads();
#pragma unroll 1
    for (int p = 0; p < 4; ++p) {
        int o = t + 256 * p, r = o >> 5, c = o & 31;
        float s = b1[c];
#pragma unroll 8
        for (int k = 0; k < 64; ++k) s += H[r * 64 + k] * W1s[k * OUTD + c];
        int row = r0 + r;
        int n = row / 3, v = row - n * 3;
        f0b[((size_t)(v << 13) + n) * RP + c] = f2bf(s);
    }
}

// ---- edge MLP + owner-computes segment mean ----
// 4 waves x 256 thr, PB=4 -> 2048 blocks; LDS ~34.2KB -> up to 4 blocks/CU
// (137KB) = 16 waves/CU if the unified reg footprint fits ~128/wave.
// launch_bounds (256,2): arch-VGPR cap 128 (calibrated R4/R5), no spill.
// Gather pipeline 2-deep (index 2 ahead, record 1 ahead).
__global__ __launch_bounds__(256, 2) void agg_kernel(
    const float* __restrict__ grid_in, const unsigned short* __restrict__ f0b,
    const int* __restrict__ posb,
    const int* __restrict__ nbr_index, const int* __restrict__ offsets,
    const int* __restrict__ counts,
    const unsigned short* __restrict__ wpack,
    const float* __restrict__ b0g, const float* __restrict__ b1g,
    const float* __restrict__ b2g,
    unsigned short* __restrict__ f1b)
{
    __shared__ __attribute__((aligned(16))) unsigned short Wls[WPACK];
    __shared__ __attribute__((aligned(16))) float bs[192];
    __shared__ __attribute__((aligned(16))) float accH[OUTD * AKP];
    __shared__ int offs[PB + 1];
    __shared__ int px2b[PB];
    __shared__ float invb[PB];

    const int t = threadIdx.x;
    const int lane = t & 63;
    const int lm = lane & 15, quad = lane >> 4;
    const int wave = t >> 6;
    const int p0 = blockIdx.x * PB;

    // stage all 31 weight fragments into LDS (31744 B)
    for (int idx = t; idx < WPACK / 8; idx += NT)
        ((int4*)Wls)[idx] = ((const int4*)wpack)[idx];
    const unsigned short* WA = Wls + lane * 8;

    for (int idx = t; idx < 192; idx += NT)
        bs[idx] = (idx < 80) ? b0g[idx] : (idx < 160 ? b1g[idx - 80] : b2g[idx - 160]);
    if (t < PB) {
        offs[t] = offsets[p0 + t];
        int c = counts[p0 + t];
        invb[t] = 1.0f / (float)(c > 1 ? c : 1);
        px2b[t] = pk2(grid_in[2 * (p0 + t)], grid_in[2 * (p0 + t) + 1]);
    }
    if (t == PB) offs[PB] = offsets[p0 + PB - 1] + counts[p0 + PB - 1];
    for (int idx = t; idx < OUTD * AKP; idx += NT) accH[idx] = 0.0f;
    __syncthreads();

    const int e0 = offs[0];
    const int cntT = offs[PB] - e0;
    const int Rb = VARS * cntT;
    const int nch = (Rb + 15) >> 4;

    // stage A: index fetch (key + nbr j) — one coalesced global load
    auto fetch_index = [&](int ch2, int& key, int& j) {
        key = -1; j = 0;
        if (ch2 < nch) {
            int myrow = (ch2 << 4) + lm;
            if (myrow < Rb) {
                int myv = (myrow >= 2 * cntT) ? 2 : ((myrow >= cntT) ? 1 : 0);
                int e = e0 + myrow - myv * cntT;
                int lp = 0;
#pragma unroll
                for (int l = 1; l < PB; ++l) lp += (e >= offs[l]);
                key = myv * PB + lp;
                j = nbr_index[e];
            }
        }
    };
    // stage B: record gather — j resident (loaded 1 iteration earlier)
    auto fetch_record = [&](int key, int j, int4& feats, int2& posf) {
        feats = make_int4(0, 0, 0, 0); posf = make_int2(0, 0);
        if (key >= 0) {
            int v = key >> 2, lp = key & 3;   // PB == 4
            feats = ((const int4*)(f0b + ((size_t)(v << 13) + j) * RP))[quad];
            if (quad == 0) posf = make_int2(posb[j], px2b[lp]);
        }
    };

    int keyA, jA, keyB, jB;
    fetch_index(wave, keyA, jA);
    fetch_index(wave + NWAVES, keyB, jB);
    int4 featsA; int2 posfA;
    fetch_record(keyA, jA, featsA, posfA);

    for (int ch = wave; ch < nch; ch += NWAVES) {
        int ckey = keyA; int4 cf = featsA; int2 cp = posfA;
        keyA = keyB; jA = jB;
        fetch_index(ch + 2 * NWAVES, keyB, jB);       // index 2 ahead
        fetch_record(keyA, jA, featsA, posfA);        // record 1 ahead
        mlp_chunk(cf, cp, WA, bs, quad, ckey, accH, AKP);
    }
    __syncthreads();
    for (int idx = t; idx < VARS * PB * OUTD; idx += NT) {
        int key = idx >> 5, c = idx & 31;
        int v = key >> 2, lp = key & 3;     // PB == 4
        size_t rec = ((size_t)(v << 13) + p0 + lp) * RP;
        float val = accH[c * AKP + key] * invb[lp] + bf2f(f0b[rec + c]);
        f1b[rec + c] = f2bf(val);
    }
}

// ---- kNN MLP + mean over K ----
// 256 thr / 4 waves, LPTS=2 -> 1024 blocks. launch_bounds (256,2):
// arch-VGPR cap 128 (same calibration), no spill.
__global__ __launch_bounds__(256, 2) void last_kernel(
    const unsigned short* __restrict__ f1b, const int* __restrict__ posb,
    const float* __restrict__ grid_out,
    const int* __restrict__ nbr_last,
    const unsigned short* __restrict__ wpack,
    const float* __restrict__ b0g, const float* __restrict__ b1g,
    const float* __restrict__ b2g,
    float* __restrict__ out)
{
    __shared__ __attribute__((aligned(16))) unsigned short Wls[WPACK];
    __shared__ __attribute__((aligned(16))) float bs[192];
    __shared__ __attribute__((aligned(16))) float accH[OUTD * LKP];
    __shared__ int pxo2b[LPTS];

    const int t = threadIdx.x;
    const int lane = t & 63;
    const int lm = lane & 15, quad = lane >> 4;
    const int wave = t >> 6;
    const int m0 = blockIdx.x * LPTS;

    for (int idx = t; idx < WPACK / 8; idx += NTL)
        ((int4*)Wls)[idx] = ((const int4*)wpack)[idx];
    const unsigned short* WA = Wls + lane * 8;

    for (int idx = t; idx < 192; idx += NTL)
        bs[idx] = (idx < 80) ? b0g[idx] : (idx < 160 ? b1g[idx - 80] : b2g[idx - 160]);
    if (t < LPTS)
        pxo2b[t] = pk2(grid_out[2 * (m0 + t)], grid_out[2 * (m0 + t) + 1]);
    for (int idx = t; idx < OUTD * LKP; idx += NTL) accH[idx] = 0.0f;
    __syncthreads();

    const int Rb = LPTS * VARS * KLAST;   // 60
    const int nch = (Rb + 15) >> 4;       // 4

    auto fetch_index = [&](int ch2, int& key, int& j) {
        key = -1; j = 0;
        if (ch2 < nch) {
            int myrow = (ch2 << 4) + lm;
            if (myrow < Rb) {
                int lp = myrow / 30, rr = myrow - lp * 30;
                int v = rr / KLAST, kk = rr - v * KLAST;
                j = nbr_last[(m0 + lp) * KLAST + kk];
                key = lp * VARS + v;
            }
        }
    };
    auto fetch_record = [&](int key, int j, int4& feats, int2& posf) {
        feats = make_int4(0, 0, 0, 0); posf = make_int2(0, 0);
        if (key >= 0) {
            int lp = key / VARS, v = key - lp * VARS;
            feats = ((const int4*)(f1b + ((size_t)(v << 13) + j) * RP))[quad];
            if (quad == 0) posf = make_int2(posb[j], pxo2b[lp]);
        }
    };

    int keyA, jA, keyB, jB;
    fetch_index(wave, keyA, jA);
    fetch_index(wave + NWL, keyB, jB);
    int4 featsA; int2 posfA;
    fetch_record(keyA, jA, featsA, posfA);

    for (int ch = wave; ch < nch; ch += NWL) {
        int ckey = keyA; int4 cf = featsA; int2 cp = posfA;
        keyA = keyB; jA = jB;
        fetch_index(ch + 2 * NWL, keyB, jB);
        fetch_record(keyA, jA, featsA, posfA);
        mlp_chunk(cf, cp, WA, bs, quad, ckey, accH, LKP);
    }
    __syncthreads();
    for (int idx = t; idx < LPTS * VARS * OUTD; idx += NTL) {
        int key = idx >> 5, c = idx & 31;
        int lp = key / VARS, v = key - lp * VARS;
        out[((size_t)(m0 + lp) * VARS + v) * OUTD + c] =
            accH[c * LKP + key] * (1.0f / KLAST);
    }
}

extern "C" void kernel_launch(void* const* d_in, const int* in_sizes, int n_in,
                              void* d_out, int out_size, void* d_ws, size_t ws_size,
                              hipStream_t stream) {
    const float* inp      = (const float*)d_in[0];
    const float* grid_in  = (const float*)d_in[1];
    const float* grid_out = (const float*)d_in[2];
    const float* pW0 = (const float*)d_in[3];
    const float* pb0 = (const float*)d_in[4];
    const float* pW1 = (const float*)d_in[5];
    const float* pb1 = (const float*)d_in[6];
    const float* i0W0 = (const float*)d_in[7];
    const float* i0b0 = (const float*)d_in[8];
    const float* i0W1 = (const float*)d_in[9];
    const float* i0b1 = (const float*)d_in[10];
    const float* i0W2 = (const float*)d_in[11];
    const float* i0b2 = (const float*)d_in[12];
    const float* i1W0 = (const float*)d_in[13];
    const float* i1b0 = (const float*)d_in[14];
    const float* i1W1 = (const float*)d_in[15];
    const float* i1b1 = (const float*)d_in[16];
    const float* i1W2 = (const float*)d_in[17];
    const float* i1b2 = (const float*)d_in[18];
    const int* nbr_index  = (const int*)d_in[19];
    const int* nbr_counts = (const int*)d_in[21];
    const int* nbr_last   = (const int*)d_in[22];

    unsigned short* f0b = (unsigned short*)d_ws;                      // 3*8192*32 bf16
    unsigned short* f1b = f0b + (size_t)VARS * N_PTS * RP;            // 3*8192*32 bf16
    int* offsets = (int*)(f1b + (size_t)VARS * N_PTS * RP);           // N ints
    int* posb    = offsets + N_PTS;                                   // N ints (bf16x2)
    unsigned short* wpack0 = (unsigned short*)(posb + N_PTS);         // 15872 bf16
    unsigned short* wpack1 = wpack0 + WPACK;                          // 15872 bf16

    proj_scan_kernel<<<771, 256, 0, stream>>>(inp, grid_in, pW0, pb0, pW1, pb1,
                                              f0b, posb, nbr_counts, offsets,
                                              i0W0, i0W1, i0W2, wpack0,
                                              i1W0, i1W1, i1W2, wpack1);
    agg_kernel<<<N_PTS / PB, NT, 0, stream>>>(grid_in, f0b, posb, nbr_index, offsets,
                                              nbr_counts, wpack0,
                                              i0b0, i0b1, i0b2, f1b);
    last_kernel<<<M_PTS / LPTS, NTL, 0, stream>>>(f1b, posb, grid_out, nbr_last, wpack1,
                                                  i1b0, i1b1, i1b2,
                                                  (float*)d_out);
}